// Round 12
// baseline (256.590 us; speedup 1.0000x reference)
//
#include <hip/hip_runtime.h>

namespace {

constexpr int S   = 2048;
constexpr int NBH = 32;    // b*h

constexpr float QSCALE = 0.18033688011112042f;   // log2(e)/8
constexpr float BIAS   = -11.541560327111708f;   // -8*log2(e)

typedef short  bf16x8 __attribute__((ext_vector_type(8)));
typedef float  f32x4  __attribute__((ext_vector_type(4)));
typedef unsigned short u16;

__device__ inline u16 f2bf(float f) {
  union { float f; unsigned u; } v; v.f = f;
  unsigned u = v.u + 0x7fffu + ((v.u >> 16) & 1u);
  return (u16)(u >> 16);
}
__device__ inline u16 f2bf_rz(float f) {
  union { float f; unsigned u; } v; v.f = f;
  return (u16)(v.u >> 16);
}
__device__ inline float fast_exp2(float x) {
#if __has_builtin(__builtin_amdgcn_exp2f)
  return __builtin_amdgcn_exp2f(x);
#else
  return exp2f(x);
#endif
}

typedef __attribute__((address_space(3))) void lds_void;
typedef const __attribute__((address_space(1))) void glb_void;
__device__ inline void load_lds16(const void* g, void* l) {
#if __has_builtin(__builtin_amdgcn_global_load_lds)
  __builtin_amdgcn_global_load_lds((glb_void*)g, (lds_void*)l, 16, 0, 0);
#else
  *(uint4*)l = *(const uint4*)g;
#endif
}

// ---- prep: unchanged (r9-verified) ----
__global__ __launch_bounds__(256) void prep(
    const float* __restrict__ K, const float* __restrict__ V,
    u16* __restrict__ Kf, u16* __restrict__ Vf) {
  const int lin = blockIdx.x;
  const int k8 = lin & 7, idx = lin >> 3;
  const int j2 = idx & 3, kt = idx >> 2;
  const int ly = 4 * k8 + j2;
  const int bh = (ly < 16) ? ly * 2 : (ly - 16) * 2 + 1;
  const int tid = threadIdx.x;
  u16* kout = Kf + (size_t)(bh * 32 + kt) * 4096;
  u16* vout = Vf + (size_t)(bh * 32 + kt) * 4096;

  constexpr int LT = 68;
  __shared__ float Kt[64 * LT];
  __shared__ float Vt[64 * LT];

#pragma unroll
  for (int i = 0; i < 4; ++i) {
    const int fid = tid + 256 * i;
    const int tok = fid >> 4, dq = fid & 15;
    const size_t goff = ((size_t)(kt * 64 + tok) * 32 + bh) * 64 + dq * 4;
    *(float4*)(Kt + tok * LT + dq * 4) = *(const float4*)(K + goff);
    *(float4*)(Vt + tok * LT + dq * 4) = *(const float4*)(V + goff);
  }
  __syncthreads();

#pragma unroll
  for (int i = 0; i < 2; ++i) {
    const int p    = tid + 256 * i;
    const int lane = p & 63, fr = p >> 6;
    const int col  = lane & 15, quad = lane >> 4;
    const int n    = fr >> 1, c = fr & 1;
    {
      const float* src = Kt + (n * 16 + col) * LT + c * 32 + quad * 8;
      const float4 a = *(const float4*)src;
      const float4 b = *(const float4*)(src + 4);
      u16 o[8] = { f2bf(a.x), f2bf(a.y), f2bf(a.z), f2bf(a.w),
                   f2bf(b.x), f2bf(b.y), f2bf(b.z), f2bf(b.w) };
      *(uint4*)(kout + (size_t)p * 8) = *(const uint4*)o;
    }
    {
      const int d = n * 16 + col;
      u16 o[8];
#pragma unroll
      for (int j = 0; j < 8; ++j) {
        const int tok = 32 * c + 16 * (j >> 2) + 4 * quad + (j & 3);
        o[j] = f2bf(Vt[tok * LT + d]);
      }
      *(uint4*)(vout + (size_t)p * 8) = *(const uint4*)o;
    }
  }
}

// ---- fa: unchanged r11 (verified) ----
__global__ __launch_bounds__(256, 4) void fa(
    const float* __restrict__ Qf_, const u16* __restrict__ Kf,
    const u16* __restrict__ Vf, float* __restrict__ Og,
    float* __restrict__ pO, float* __restrict__ pL) {
  const int lin = blockIdx.x;
  const int xcd = lin & 7, m = lin >> 3;
  const int j = m & 3, u = m >> 2;
  const int pr = u >> 1, h = u & 1;
  const int qbA = pr, qbB = 31 - pr;
  const int ly = 4 * xcd + j;
  const int bh = (ly < 16) ? ly * 2 : (ly - 16) * 2 + 1;
  const int bi = bh >> 4, hi = bh & 15;
  const int tid = threadIdx.x, lane = tid & 63, w = tid >> 6;
  const int col = lane & 15, quad = lane >> 4;

  __shared__ u16 Ks[2][4096];
  __shared__ u16 Vs[2][4096];

  const u16* kbase = Kf + (size_t)bh * 32 * 4096;
  const u16* vbase = Vf + (size_t)bh * 32 * 4096;

  bf16x8 onesA;
#pragma unroll
  for (int j2 = 0; j2 < 8; ++j2) onesA[j2] = (short)0x3F80;

  bf16x8 qf[2];
  f32x4 Oacc[4], Lacc;

  auto load_q = [&](int qbE) {
    const int row = qbE * 64 + w * 16 + col;
    const float* q = Qf_ + (size_t)row * 2048 + bi * 1024 + hi * 64;
#pragma unroll
    for (int c = 0; c < 2; ++c) {
      const float4 a = *(const float4*)(q + c * 32 + quad * 8);
      const float4 b = *(const float4*)(q + c * 32 + quad * 8 + 4);
      u16 o[8] = { f2bf(a.x * QSCALE), f2bf(a.y * QSCALE),
                   f2bf(a.z * QSCALE), f2bf(a.w * QSCALE),
                   f2bf(b.x * QSCALE), f2bf(b.y * QSCALE),
                   f2bf(b.z * QSCALE), f2bf(b.w * QSCALE) };
      qf[c] = *(const bf16x8*)o;
    }
  };
  auto stage4 = [&](int kt, int buf) {
    const u16* kg = kbase + (size_t)kt * 4096;
    const u16* vg = vbase + (size_t)kt * 4096;
    load_lds16(kg + (size_t)tid * 8,         Ks[buf] + (size_t)tid * 8);
    load_lds16(kg + (size_t)(tid + 256) * 8, Ks[buf] + (size_t)(tid + 256) * 8);
    load_lds16(vg + (size_t)tid * 8,         Vs[buf] + (size_t)tid * 8);
    load_lds16(vg + (size_t)(tid + 256) * 8, Vs[buf] + (size_t)(tid + 256) * 8);
  };

  auto run = [&](int qbE, int kt0, int kt1) {
    Lacc = (f32x4){0.f, 0.f, 0.f, 0.f};
#pragma unroll
    for (int n = 0; n < 4; ++n) Oacc[n] = (f32x4){0.f, 0.f, 0.f, 0.f};
    __syncthreads();
    stage4(kt0, kt0 & 1);
    for (int kt = kt0; kt < kt1; ++kt) {
      __syncthreads();
      if (kt + 1 < kt1) stage4(kt + 1, (kt + 1) & 1);
      const u16* ks = Ks[kt & 1];
      const u16* vs = Vs[kt & 1];

      bf16x8 kf[4][2];
#pragma unroll
      for (int kb = 0; kb < 4; ++kb) {
        kf[kb][0] = *(const bf16x8*)(ks + (kb * 2 + 0) * 512 + lane * 8);
        kf[kb][1] = *(const bf16x8*)(ks + (kb * 2 + 1) * 512 + lane * 8);
      }
      f32x4 Sacc[4];
#pragma unroll
      for (int kb = 0; kb < 4; ++kb) {
        f32x4 z = (f32x4){BIAS, BIAS, BIAS, BIAS};
        z = __builtin_amdgcn_mfma_f32_16x16x32_bf16(kf[kb][0], qf[0], z, 0, 0, 0);
        Sacc[kb] = __builtin_amdgcn_mfma_f32_16x16x32_bf16(kf[kb][1], qf[1], z, 0, 0, 0);
      }
      bf16x8 va[4][2];
#pragma unroll
      for (int nd = 0; nd < 4; ++nd) {
        va[nd][0] = *(const bf16x8*)(vs + (nd * 2 + 0) * 512 + lane * 8);
        va[nd][1] = *(const bf16x8*)(vs + (nd * 2 + 1) * 512 + lane * 8);
      }

      if (kt == qbE) {
        const int qrow = w * 16 + col;
#pragma unroll
        for (int kb = 0; kb < 4; ++kb) {
          const int key = kb * 16 + quad * 4;
#pragma unroll
          for (int r = 0; r < 4; ++r)
            if (key + r > qrow) Sacc[kb][r] = -1e30f;
        }
      }

      u16 pu[4][4];
#pragma unroll
      for (int kb = 0; kb < 4; ++kb)
#pragma unroll
        for (int r = 0; r < 4; ++r)
          pu[kb][r] = f2bf_rz(fast_exp2(Sacc[kb][r]));
      bf16x8 pa[2];
#pragma unroll
      for (int kc = 0; kc < 2; ++kc)
#pragma unroll
        for (int jj = 0; jj < 8; ++jj)
          pa[kc][jj] = (short)pu[2 * kc + (jj >> 2)][jj & 3];

#pragma unroll
      for (int nd = 0; nd < 4; ++nd) {
        Oacc[nd] = __builtin_amdgcn_mfma_f32_16x16x32_bf16(va[nd][0], pa[0], Oacc[nd], 0, 0, 0);
        Oacc[nd] = __builtin_amdgcn_mfma_f32_16x16x32_bf16(va[nd][1], pa[1], Oacc[nd], 0, 0, 0);
      }
      Lacc = __builtin_amdgcn_mfma_f32_16x16x32_bf16(onesA, pa[0], Lacc, 0, 0, 0);
      Lacc = __builtin_amdgcn_mfma_f32_16x16x32_bf16(onesA, pa[1], Lacc, 0, 0, 0);
    }
  };

  if (h == 0) {
    load_q(qbA);
    run(qbA, 0, qbA + 1);
    const float rl = 1.f / Lacc[0];
    const int row = qbA * 64 + w * 16 + col;
    float* o = Og + ((size_t)(row * 2 + bi) * 16 + hi) * 64;
#pragma unroll
    for (int nd = 0; nd < 4; ++nd) {
      float4 v;
      v.x = Oacc[nd][0] * rl; v.y = Oacc[nd][1] * rl;
      v.z = Oacc[nd][2] * rl; v.w = Oacc[nd][3] * rl;
      *(float4*)(o + nd * 16 + quad * 4) = v;
    }
  }

  {
    const int mid = 16 - pr;
    const int kt0 = h ? mid : 0;
    const int kt1 = h ? (qbB + 1) : mid;
    load_q(qbB);
    run(qbB, kt0, kt1);

    const int unit = bh * 16 + pr;
    float* po = pO + (size_t)(unit * 2 + h) * 4096;
    const int row = w * 16 + col;
#pragma unroll
    for (int nd = 0; nd < 4; ++nd) {
      float4 v;
      v.x = Oacc[nd][0]; v.y = Oacc[nd][1];
      v.z = Oacc[nd][2]; v.w = Oacc[nd][3];
      *(float4*)(po + (size_t)row * 64 + nd * 16 + quad * 4) = v;
    }
    if (quad == 0)
      pL[(size_t)(unit * 2 + h) * 64 + row] = Lacc[0];
  }
}

// ---- combine: unchanged r11 ----
__global__ __launch_bounds__(256) void combine(
    const float* __restrict__ pO, const float* __restrict__ pL,
    float* __restrict__ Og) {
  const int unit = blockIdx.x;
  const int bh = unit >> 4, pr = unit & 15;
  const int qbB = 31 - pr;
  const int bi = bh >> 4, hi = bh & 15;
  const int tid = threadIdx.x;
  const int row = tid >> 2, dq = (tid & 3) * 16;

  const float l = pL[(size_t)(unit * 2 + 0) * 64 + row] +
                  pL[(size_t)(unit * 2 + 1) * 64 + row];
  const float rl = 1.f / l;
  const float* a = pO + (size_t)(unit * 2 + 0) * 4096 + row * 64 + dq;
  const float* b = pO + (size_t)(unit * 2 + 1) * 4096 + row * 64 + dq;
  const int grow = qbB * 64 + row;
  float* o = Og + ((size_t)(grow * 2 + bi) * 16 + hi) * 64 + dq;
#pragma unroll
  for (int dd = 0; dd < 4; ++dd) {
    const float4 x = *(const float4*)(a + dd * 4);
    const float4 y = *(const float4*)(b + dd * 4);
    float4 z;
    z.x = (x.x + y.x) * rl; z.y = (x.y + y.y) * rl;
    z.z = (x.z + y.z) * rl; z.w = (x.w + y.w) * rl;
    *(float4*)(o + dd * 4) = z;
  }
}

// ======================= DIAGNOSTIC KERNELS =======================
// Run AFTER combine; write only to scratch.  2x/6x repetition pushes them
// above the ~43us fill cutoff so their rocprof counters become visible.
// MODE 0: full fa body.  MODE 1: exp/pack removed (pa := qf, Sacc kept
// alive via empty asm — rule #17 anti-DCE).  D0/2 = fa true cost + true
// counters; (D0-D1)/2 = exp+pack chain cost.
template <int MODE>
__global__ __launch_bounds__(256, 4) void fa_diag(
    const float* __restrict__ Qf_, const u16* __restrict__ Kf,
    const u16* __restrict__ Vf, float* __restrict__ pD) {
  const int lin = blockIdx.x;
  const int xcd = lin & 7, m = lin >> 3;
  const int j = m & 3, u = m >> 2;
  const int pr = u >> 1, h = u & 1;
  const int qbA = pr, qbB = 31 - pr;
  const int ly = 4 * xcd + j;
  const int bh = (ly < 16) ? ly * 2 : (ly - 16) * 2 + 1;
  const int bi = bh >> 4, hi = bh & 15;
  const int tid = threadIdx.x, lane = tid & 63, w = tid >> 6;
  const int col = lane & 15, quad = lane >> 4;

  __shared__ u16 Ks[2][4096];
  __shared__ u16 Vs[2][4096];

  const u16* kbase = Kf + (size_t)bh * 32 * 4096;
  const u16* vbase = Vf + (size_t)bh * 32 * 4096;

  bf16x8 onesA;
#pragma unroll
  for (int j2 = 0; j2 < 8; ++j2) onesA[j2] = (short)0x3F80;

  bf16x8 qf[2];
  f32x4 Oacc[4], Lacc;

  auto load_q = [&](int qbE) {
    const int row = qbE * 64 + w * 16 + col;
    const float* q = Qf_ + (size_t)row * 2048 + bi * 1024 + hi * 64;
#pragma unroll
    for (int c = 0; c < 2; ++c) {
      const float4 a = *(const float4*)(q + c * 32 + quad * 8);
      const float4 b = *(const float4*)(q + c * 32 + quad * 8 + 4);
      u16 o[8] = { f2bf(a.x * QSCALE), f2bf(a.y * QSCALE),
                   f2bf(a.z * QSCALE), f2bf(a.w * QSCALE),
                   f2bf(b.x * QSCALE), f2bf(b.y * QSCALE),
                   f2bf(b.z * QSCALE), f2bf(b.w * QSCALE) };
      qf[c] = *(const bf16x8*)o;
    }
  };
  auto stage4 = [&](int kt, int buf) {
    const u16* kg = kbase + (size_t)kt * 4096;
    const u16* vg = vbase + (size_t)kt * 4096;
    load_lds16(kg + (size_t)tid * 8,         Ks[buf] + (size_t)tid * 8);
    load_lds16(kg + (size_t)(tid + 256) * 8, Ks[buf] + (size_t)(tid + 256) * 8);
    load_lds16(vg + (size_t)tid * 8,         Vs[buf] + (size_t)tid * 8);
    load_lds16(vg + (size_t)(tid + 256) * 8, Vs[buf] + (size_t)(tid + 256) * 8);
  };

  auto run = [&](int qbE, int kt0, int kt1) {
    Lacc = (f32x4){0.f, 0.f, 0.f, 0.f};
#pragma unroll
    for (int n = 0; n < 4; ++n) Oacc[n] = (f32x4){0.f, 0.f, 0.f, 0.f};
    __syncthreads();
    stage4(kt0, kt0 & 1);
    for (int kt = kt0; kt < kt1; ++kt) {
      __syncthreads();
      if (kt + 1 < kt1) stage4(kt + 1, (kt + 1) & 1);
      const u16* ks = Ks[kt & 1];
      const u16* vs = Vs[kt & 1];

      bf16x8 kf[4][2];
#pragma unroll
      for (int kb = 0; kb < 4; ++kb) {
        kf[kb][0] = *(const bf16x8*)(ks + (kb * 2 + 0) * 512 + lane * 8);
        kf[kb][1] = *(const bf16x8*)(ks + (kb * 2 + 1) * 512 + lane * 8);
      }
      f32x4 Sacc[4];
#pragma unroll
      for (int kb = 0; kb < 4; ++kb) {
        f32x4 z = (f32x4){BIAS, BIAS, BIAS, BIAS};
        z = __builtin_amdgcn_mfma_f32_16x16x32_bf16(kf[kb][0], qf[0], z, 0, 0, 0);
        Sacc[kb] = __builtin_amdgcn_mfma_f32_16x16x32_bf16(kf[kb][1], qf[1], z, 0, 0, 0);
      }
      bf16x8 va[4][2];
#pragma unroll
      for (int nd = 0; nd < 4; ++nd) {
        va[nd][0] = *(const bf16x8*)(vs + (nd * 2 + 0) * 512 + lane * 8);
        va[nd][1] = *(const bf16x8*)(vs + (nd * 2 + 1) * 512 + lane * 8);
      }

      if (kt == qbE) {
        const int qrow = w * 16 + col;
#pragma unroll
        for (int kb = 0; kb < 4; ++kb) {
          const int key = kb * 16 + quad * 4;
#pragma unroll
          for (int r = 0; r < 4; ++r)
            if (key + r > qrow) Sacc[kb][r] = -1e30f;
        }
      }

      bf16x8 pa[2];
      if constexpr (MODE == 0) {
        u16 pu[4][4];
#pragma unroll
        for (int kb = 0; kb < 4; ++kb)
#pragma unroll
          for (int r = 0; r < 4; ++r)
            pu[kb][r] = f2bf_rz(fast_exp2(Sacc[kb][r]));
#pragma unroll
        for (int kc = 0; kc < 2; ++kc)
#pragma unroll
          for (int jj = 0; jj < 8; ++jj)
            pa[kc][jj] = (short)pu[2 * kc + (jj >> 2)][jj & 3];
      } else {
        // keep QK results live without exp/pack (anti-DCE, rule #17)
#pragma unroll
        for (int kb = 0; kb < 4; ++kb)
          asm volatile("" :: "v"(Sacc[kb][0]), "v"(Sacc[kb][1]),
                            "v"(Sacc[kb][2]), "v"(Sacc[kb][3]));
        pa[0] = qf[0]; pa[1] = qf[1];
      }

#pragma unroll
      for (int nd = 0; nd < 4; ++nd) {
        Oacc[nd] = __builtin_amdgcn_mfma_f32_16x16x32_bf16(va[nd][0], pa[0], Oacc[nd], 0, 0, 0);
        Oacc[nd] = __builtin_amdgcn_mfma_f32_16x16x32_bf16(va[nd][1], pa[1], Oacc[nd], 0, 0, 0);
      }
      Lacc = __builtin_amdgcn_mfma_f32_16x16x32_bf16(onesA, pa[0], Lacc, 0, 0, 0);
      Lacc = __builtin_amdgcn_mfma_f32_16x16x32_bf16(onesA, pa[1], Lacc, 0, 0, 0);
    }
  };

  for (int rep = 0; rep < 2; ++rep) {
    if (h == 0) {
      load_q(qbA);
      run(qbA, 0, qbA + 1);
      float* po = pD + (size_t)(lin * 2 + 0) * 4096;
      const int row = w * 16 + col;
#pragma unroll
      for (int nd = 0; nd < 4; ++nd) {
        float4 v;
        v.x = Oacc[nd][0]; v.y = Oacc[nd][1];
        v.z = Oacc[nd][2]; v.w = Oacc[nd][3] + Lacc[0];
        *(float4*)(po + (size_t)row * 64 + nd * 16 + quad * 4) = v;
      }
    }
    {
      const int mid = 16 - pr;
      const int kt0 = h ? mid : 0;
      const int kt1 = h ? (qbB + 1) : mid;
      load_q(qbB);
      run(qbB, kt0, kt1);
      float* po = pD + (size_t)(lin * 2 + 1) * 4096;
      const int row = w * 16 + col;
#pragma unroll
      for (int nd = 0; nd < 4; ++nd) {
        float4 v;
        v.x = Oacc[nd][0]; v.y = Oacc[nd][1];
        v.z = Oacc[nd][2]; v.w = Oacc[nd][3] + Lacc[0];
        *(float4*)(po + (size_t)row * 64 + nd * 16 + quad * 4) = v;
      }
    }
  }
}

// prep x6 into scratch: prep true cost = dur/6.
__global__ __launch_bounds__(256) void prep_diag(
    const float* __restrict__ K, const float* __restrict__ V,
    u16* __restrict__ Ks_, u16* __restrict__ Vs_) {
  const int lin = blockIdx.x;
  const int k8 = lin & 7, idx = lin >> 3;
  const int j2 = idx & 3, kt = idx >> 2;
  const int ly = 4 * k8 + j2;
  const int bh = (ly < 16) ? ly * 2 : (ly - 16) * 2 + 1;
  const int tid = threadIdx.x;
  u16* kout = Ks_ + (size_t)(bh * 32 + kt) * 4096;
  u16* vout = Vs_ + (size_t)(bh * 32 + kt) * 4096;

  constexpr int LT = 68;
  __shared__ float Kt[64 * LT];
  __shared__ float Vt[64 * LT];

  for (int rep = 0; rep < 6; ++rep) {
#pragma unroll
    for (int i = 0; i < 4; ++i) {
      const int fid = tid + 256 * i;
      const int tok = fid >> 4, dq = fid & 15;
      const size_t goff = ((size_t)(kt * 64 + tok) * 32 + bh) * 64 + dq * 4;
      *(float4*)(Kt + tok * LT + dq * 4) = *(const float4*)(K + goff);
      *(float4*)(Vt + tok * LT + dq * 4) = *(const float4*)(V + goff);
    }
    __syncthreads();

#pragma unroll
    for (int i = 0; i < 2; ++i) {
      const int p    = tid + 256 * i;
      const int lane = p & 63, fr = p >> 6;
      const int col  = lane & 15, quad = lane >> 4;
      const int n    = fr >> 1, c = fr & 1;
      {
        const float* src = Kt + (n * 16 + col) * LT + c * 32 + quad * 8;
        const float4 a = *(const float4*)src;
        const float4 b = *(const float4*)(src + 4);
        u16 o[8] = { f2bf(a.x), f2bf(a.y), f2bf(a.z), f2bf(a.w),
                     f2bf(b.x), f2bf(b.y), f2bf(b.z), f2bf(b.w) };
        *(uint4*)(kout + (size_t)p * 8) = *(const uint4*)o;
      }
      {
        const int d = n * 16 + col;
        u16 o[8];
#pragma unroll
        for (int j = 0; j < 8; ++j) {
          const int tok = 32 * c + 16 * (j >> 2) + 4 * quad + (j & 3);
          o[j] = f2bf(Vt[tok * LT + d]);
        }
        *(uint4*)(vout + (size_t)p * 8) = *(const uint4*)o;
      }
    }
    __syncthreads();   // gathers done before next rep restages Kt/Vt
  }
}

}  // namespace

extern "C" void kernel_launch(void* const* d_in, const int* in_sizes, int n_in,
                              void* d_out, int out_size, void* d_ws, size_t ws_size,
                              hipStream_t stream) {
  const float* Q = (const float*)d_in[0];
  const float* K = (const float*)d_in[1];
  const float* V = (const float*)d_in[2];
  float* O = (float*)d_out;

  u16* Kf = (u16*)d_ws;                      // 8.4 MB
  u16* Vf = Kf + (size_t)NBH * 32 * 4096;    // 8.4 MB
  float* pO = (float*)(Vf + (size_t)NBH * 32 * 4096);   // 16.8 MB
  float* pL = pO + (size_t)1024 * 4096;                 // 256 KB
  float* pD = pL + (size_t)1024 * 64;                   // 33.6 MB diag scratch
  u16*   pS = (u16*)(pD + (size_t)2048 * 4096);         // 16.8 MB prep scratch

  // real computation (unchanged r11 path)
  prep<<<dim3(1024), 256, 0, stream>>>(K, V, Kf, Vf);
  fa<<<dim3(1024), 256, 0, stream>>>(Q, Kf, Vf, O, pO, pL);
  combine<<<dim3(512), 256, 0, stream>>>(pO, pL, O);

  // diagnostics (scratch-only; visible above the fill cutoff via 2x/6x rep)
  prep_diag<<<dim3(1024), 256, 0, stream>>>(K, V, pS, pS + (size_t)NBH * 32 * 4096 / 1);
  fa_diag<0><<<dim3(1024), 256, 0, stream>>>(Q, Kf, Vf, pD);
  fa_diag<1><<<dim3(1024), 256, 0, stream>>>(Q, Kf, Vf, pD);
}